// Round 13
// baseline (767.998 us; speedup 1.0000x reference)
//
#include <hip/hip_runtime.h>
#include <hip/hip_bf16.h>
#include <math.h>

typedef __hip_bfloat16 bf16;
typedef __attribute__((ext_vector_type(8))) short bf16x8_t;   // MFMA A/B frag (4 VGPRs)
typedef __attribute__((ext_vector_type(4))) short bf16x4_t;
typedef __attribute__((ext_vector_type(4))) float f32x4_t;    // MFMA C/D frag

// ---------------- constants ----------------
#define BN_RDENOM 0.9999950000374997f   // 1/sqrt(1+1e-5)
#define EPS_LN 1e-5f
#define ATTN_SCALE 0.17677669529663687f // 1/sqrt(32)
#define S_LEN 1025
#define S_PAD 1088                      // 17*64, for unconditional chunked loads
#define E_DIM 256
#define NHEAD 8
#define HDIM 32
#define MROWS (8 * S_LEN)               // 8200
#define M_PAD 8320                      // 65*128: flat-m V^T row length (>= 7*1025+1088)
#define WSLOT 786432                    // bf16 elems per layer weight slot

__device__ __forceinline__ float bf(const bf16 v) { return __bfloat162float(v); }
__device__ __forceinline__ bf16 tobf(float v) { return __float2bfloat16(v); }
__device__ __forceinline__ short bfbits(float v) {
    bf16 t = __float2bfloat16(v); short s; __builtin_memcpy(&s, &t, 2); return s;
}
__device__ __forceinline__ float gelu_exact(float x) {
    return 0.5f * x * (1.0f + erff(x * 0.70710678118654752f));
}

// async global->LDS, 16B per lane. LDS dest = wave-uniform base + 16*lane (HW rule);
// the global source is per-lane (pre-swizzled by the caller).
__device__ __forceinline__ void gl_lds16(const bf16* g, short* l)
{
    __builtin_amdgcn_global_load_lds(
        (const __attribute__((address_space(1))) unsigned int*)g,
        (__attribute__((address_space(3))) unsigned int*)l, 16, 0, 0);
}

// ---------------- weight conversion fp32 -> bf16 ----------------
__global__ __launch_bounds__(256) void cvt_w(const float* __restrict__ src,
    bf16* __restrict__ dst, int n)
{
    int i = (blockIdx.x * 256 + threadIdx.x) * 4;
    if (i >= n) return;
    f32x4_t v = *(const f32x4_t*)(src + i);
    bf16x4_t o;
    #pragma unroll
    for (int j = 0; j < 4; ++j) o[j] = bfbits(v[j]);
    *(bf16x4_t*)((short*)dst + i) = o;
}

// all six weight tensors of one layer into one slot, ALL LAYERS in one dispatch:
// grid (768, 6); blockIdx.y = layer. [Wq 64K][Wk 64K][Wv 64K][Wo 64K][W1 256K][W2 256K].
__global__ __launch_bounds__(256) void cvt_layer6(const float* __restrict__ wq,
    const float* __restrict__ wk, const float* __restrict__ wv, const float* __restrict__ wo,
    const float* __restrict__ w1, const float* __restrict__ w2, bf16* __restrict__ dst)
{
    int l = blockIdx.y;
    int i = (blockIdx.x * 256 + threadIdx.x) * 4;
    const float* s; int off;
    if (i < 262144) {
        s = (i < 65536) ? wq : (i < 131072) ? wk : (i < 196608) ? wv : wo;
        s += (size_t)l * 65536;
        off = i & 65535;
    } else if (i < 524288) { s = w1 + (size_t)l * 262144; off = i - 262144; }
    else                   { s = w2 + (size_t)l * 262144; off = i - 524288; }
    f32x4_t v = *(const f32x4_t*)(s + off);
    bf16x4_t o;
    #pragma unroll
    for (int j = 0; j < 4; ++j) o[j] = bfbits(v[j]);
    *(bf16x4_t*)((short*)dst + (size_t)l * WSLOT + i) = o;
}

// ---------------- conv block 1 ----------------
__global__ __launch_bounds__(256) void conv_sep1(const float* __restrict__ x,
    const float* __restrict__ dw, const float* __restrict__ pw,
    const float* __restrict__ g, const float* __restrict__ bb,
    bf16* __restrict__ out)
{
    __shared__ float xs[70][64];
    __shared__ float dy[32][64];
    __shared__ float pws[64][65];
    __shared__ float dws[64][7];
    int blk = blockIdx.x;
    int tile = blk & 63, b = blk >> 6;
    int t0 = tile * 32;
    int tid = threadIdx.x;
    int tbase = t0 * 2 - 3;
    for (int i = tid; i < 70 * 64; i += 256) {
        int r = i >> 6, c = i & 63;
        int t = tbase + r;
        xs[r][c] = (t >= 0 && t < 4096) ? x[((size_t)b * 4096 + t) * 64 + c] : 0.f;
    }
    for (int i = tid; i < 64 * 7; i += 256) dws[i / 7][i % 7] = dw[i];
    for (int i = tid; i < 64 * 64; i += 256) pws[i >> 6][i & 63] = pw[i];
    __syncthreads();
    for (int i = tid; i < 32 * 64; i += 256) {
        int tl = i >> 6, c = i & 63;
        float s = 0.f;
        #pragma unroll
        for (int j = 0; j < 7; ++j) s += xs[2 * tl + j][c] * dws[c][j];
        dy[tl][c] = s;
    }
    __syncthreads();
    for (int i = tid; i < 32 * 64; i += 256) {
        int tl = i >> 6, o = i & 63;
        float s = 0.f;
        #pragma unroll 8
        for (int c = 0; c < 64; ++c) s += dy[tl][c] * pws[o][c];
        s = s * BN_RDENOM * g[o] + bb[o];
        out[((size_t)(b * 2048 + t0 + tl)) * 64 + o] = tobf(gelu_exact(s));
    }
}

// ---------------- conv block 2 ----------------
__global__ __launch_bounds__(256) void conv_sep2(const bf16* __restrict__ x,
    const float* __restrict__ dw, const float* __restrict__ pw,
    const float* __restrict__ g, const float* __restrict__ bb,
    bf16* __restrict__ out)
{
    __shared__ float xs[70][64];
    __shared__ float dy[32][64];
    __shared__ float pws[128][65];
    __shared__ float dws[64][7];
    int blk = blockIdx.x;
    int tile = blk & 31, b = blk >> 5;
    int t0 = tile * 32;
    int tid = threadIdx.x;
    int tbase = t0 * 2 - 3;
    for (int i = tid; i < 70 * 64; i += 256) {
        int r = i >> 6, c = i & 63;
        int t = tbase + r;
        xs[r][c] = (t >= 0 && t < 2048) ? bf(x[((size_t)b * 2048 + t) * 64 + c]) : 0.f;
    }
    for (int i = tid; i < 64 * 7; i += 256) dws[i / 7][i % 7] = dw[i];
    for (int i = tid; i < 128 * 64; i += 256) pws[i >> 6][i & 63] = pw[i];
    __syncthreads();
    for (int i = tid; i < 32 * 64; i += 256) {
        int tl = i >> 6, c = i & 63;
        float s = 0.f;
        #pragma unroll
        for (int j = 0; j < 7; ++j) s += xs[2 * tl + j][c] * dws[c][j];
        dy[tl][c] = s;
    }
    __syncthreads();
    for (int i = tid; i < 32 * 128; i += 256) {
        int tl = i >> 7, o = i & 127;
        float s = 0.f;
        #pragma unroll 8
        for (int c = 0; c < 64; ++c) s += dy[tl][c] * pws[o][c];
        s = s * BN_RDENOM * g[o] + bb[o];
        out[((size_t)(b * 1024 + t0 + tl)) * 128 + o] = tobf(gelu_exact(s));
    }
}

// ---------------- MFMA GEMM (R12-measured): all-bf16, BK=64, 64x64 tile ----------------
// (used once for the conv->proj GEMM; left unchanged)
template <int ACT>
__global__ __launch_bounds__(256) void gemm_bf(const bf16* __restrict__ A,
    const bf16* __restrict__ W, const float* __restrict__ bias,
    bf16* __restrict__ C, int M, int N, int K)
{
    __shared__ short As[64 * 72];
    __shared__ short Bs[64 * 72];
    int tid = threadIdx.x;
    int wave = tid >> 6, lane = tid & 63, quad = lane >> 4, l16 = lane & 15;
    int wm = wave & 1, wn = wave >> 1;
    int m0 = blockIdx.x * 64, n0 = blockIdx.y * 64;

    f32x4_t zero4 = {0.f, 0.f, 0.f, 0.f};
    f32x4_t acc[2][2];
    acc[0][0] = zero4; acc[0][1] = zero4; acc[1][0] = zero4; acc[1][1] = zero4;

    int srow = tid >> 2, skc = (tid & 3) * 16;
    for (int k0 = 0; k0 < K; k0 += 64) {
        {
            int m = m0 + srow;
            bf16x8_t a0 = {}, a1 = {};
            if (m < M) {
                a0 = *(const bf16x8_t*)(A + (size_t)m * K + k0 + skc);
                a1 = *(const bf16x8_t*)(A + (size_t)m * K + k0 + skc + 8);
            }
            *(bf16x8_t*)(&As[srow * 72 + skc])     = a0;
            *(bf16x8_t*)(&As[srow * 72 + skc + 8]) = a1;
        }
        {
            const bf16* wp = W + (size_t)(n0 + srow) * K + k0 + skc;
            *(bf16x8_t*)(&Bs[srow * 72 + skc])     = *(const bf16x8_t*)(wp);
            *(bf16x8_t*)(&Bs[srow * 72 + skc + 8]) = *(const bf16x8_t*)(wp + 8);
        }
        __syncthreads();
        #pragma unroll
        for (int ks = 0; ks < 2; ++ks) {
            bf16x8_t a[2], b[2];
            #pragma unroll
            for (int mi = 0; mi < 2; ++mi)
                a[mi] = *(bf16x8_t*)(&As[(wm * 32 + mi * 16 + l16) * 72 + ks * 32 + quad * 8]);
            #pragma unroll
            for (int ni = 0; ni < 2; ++ni)
                b[ni] = *(bf16x8_t*)(&Bs[(wn * 32 + ni * 16 + l16) * 72 + ks * 32 + quad * 8]);
            #pragma unroll
            for (int mi = 0; mi < 2; ++mi)
                #pragma unroll
                for (int ni = 0; ni < 2; ++ni)
                    acc[mi][ni] = __builtin_amdgcn_mfma_f32_16x16x32_bf16(a[mi], b[ni], acc[mi][ni], 0, 0, 0);
        }
        __syncthreads();
    }
    #pragma unroll
    for (int mi = 0; mi < 2; ++mi) {
        #pragma unroll
        for (int ni = 0; ni < 2; ++ni) {
            int col = n0 + wn * 32 + ni * 16 + l16;
            float bv = bias[col];
            #pragma unroll
            for (int r = 0; r < 4; ++r) {
                int row = m0 + wm * 32 + mi * 16 + quad * 4 + r;
                if (row < M) {
                    float v = acc[mi][ni][r] + bv;
                    if (ACT == 1) v = gelu_exact(v);
                    C[(size_t)row * N + col] = tobf(v);
                }
            }
        }
    }
}

// ---------------- MFMA GEMM 128x64 (MLP-up) v3: global_load_lds(16) + XOR swizzle -----
// Linear LDS (stride 64, no pad) as required by gload_lds (dest = base + 16*lane);
// bank conflicts on fragment reads avoided by pre-swizzling the GLOBAL source column
// block (cb ^= row&7, stays coalesced within the 128B line) and applying the same XOR
// on reads (T2 both-sides rule). OOB A-rows clamp to M-1 (finite; outputs masked).
template <int ACT>
__global__ __launch_bounds__(256) void gemm_bf128(const bf16* __restrict__ A,
    const bf16* __restrict__ W, const float* __restrict__ bias,
    bf16* __restrict__ C, int M, int N, int K)
{
    __shared__ short As[128 * 64];   // 16KB linear
    __shared__ short Bs[64 * 64];    // 8KB linear
    int tid = threadIdx.x;
    int wave = tid >> 6, lane = tid & 63, quad = lane >> 4, l16 = lane & 15;
    int wm = wave & 1, wn = wave >> 1;
    int m0 = blockIdx.x * 128, n0 = blockIdx.y * 64;

    f32x4_t zero4 = {0.f, 0.f, 0.f, 0.f};
    f32x4_t acc[4][2];
    #pragma unroll
    for (int i = 0; i < 4; ++i) { acc[i][0] = zero4; acc[i][1] = zero4; }

    int lr8 = lane >> 3, lcb = lane & 7;

    for (int k0 = 0; k0 < K; k0 += 64) {
        #pragma unroll
        for (int i = 0; i < 4; ++i) {            // A: 4 insts/wave, 8 rows each
            int row = (wave * 4 + i) * 8 + lr8;
            int m = m0 + row; if (m >= M) m = M - 1;
            int cb = lcb ^ (row & 7);
            gl_lds16(A + (size_t)m * K + k0 + cb * 8, &As[(wave * 4 + i) * 512]);
        }
        #pragma unroll
        for (int i = 0; i < 2; ++i) {            // B: 2 insts/wave
            int row = (wave * 2 + i) * 8 + lr8;
            int cb = lcb ^ (row & 7);
            gl_lds16(W + (size_t)(n0 + row) * K + k0 + cb * 8, &Bs[(wave * 2 + i) * 512]);
        }
        __syncthreads();                          // drains vmcnt -> LDS valid
        #pragma unroll
        for (int ks = 0; ks < 2; ++ks) {
            bf16x8_t a[4], b[2];
            #pragma unroll
            for (int mi = 0; mi < 4; ++mi) {
                int row = wm * 64 + mi * 16 + l16;
                a[mi] = *(bf16x8_t*)(&As[row * 64 + ((ks * 4 + quad) ^ (row & 7)) * 8]);
            }
            #pragma unroll
            for (int ni = 0; ni < 2; ++ni) {
                int row = wn * 32 + ni * 16 + l16;
                b[ni] = *(bf16x8_t*)(&Bs[row * 64 + ((ks * 4 + quad) ^ (row & 7)) * 8]);
            }
            #pragma unroll
            for (int mi = 0; mi < 4; ++mi)
                #pragma unroll
                for (int ni = 0; ni < 2; ++ni)
                    acc[mi][ni] = __builtin_amdgcn_mfma_f32_16x16x32_bf16(a[mi], b[ni], acc[mi][ni], 0, 0, 0);
        }
        __syncthreads();
    }
    #pragma unroll
    for (int mi = 0; mi < 4; ++mi) {
        #pragma unroll
        for (int ni = 0; ni < 2; ++ni) {
            int col = n0 + wn * 32 + ni * 16 + l16;
            float bv = bias[col];
            #pragma unroll
            for (int r = 0; r < 4; ++r) {
                int row = m0 + wm * 64 + mi * 16 + quad * 4 + r;
                if (row < M) {
                    float v = acc[mi][ni][r] + bv;
                    if (ACT == 1) v = gelu_exact(v);
                    C[(size_t)row * N + col] = tobf(v);
                }
            }
        }
    }
}

// ---------------- fused GEMM (N=256) + bias + residual + LayerNorm (512 thr) -----------
// 32 rows x 256 cols per block, 8 waves each 32x32 -> 2 waves/SIMD at 1 block/CU.
// Register prefetch kept HERE (1 block/CU: no TLP to hide staging latency).
template <int RES>
__global__ __launch_bounds__(512) void gemm_resln(const bf16* __restrict__ A,
    const bf16* __restrict__ W, const float* __restrict__ bias,
    const bf16* __restrict__ R, const float* __restrict__ g,
    const float* __restrict__ bb, bf16* __restrict__ out, int M, int K)
{
    const int N = 256;
    __shared__ short As[32 * 72];
    __shared__ short Bs[256 * 72];
    __shared__ float red[2][32][8];
    int tid = threadIdx.x;
    int wave = tid >> 6, lane = tid & 63, quad = lane >> 4, l16 = lane & 15;
    int m0 = blockIdx.x * 32;

    f32x4_t zero4 = {0.f, 0.f, 0.f, 0.f};
    f32x4_t acc[2][2];
    acc[0][0] = zero4; acc[0][1] = zero4; acc[1][0] = zero4; acc[1][1] = zero4;

    int sr = tid >> 3, skc = (tid & 7) * 8;
    int am = m0 + sr; if (am >= M) am = M - 1;   // clamp: finite, rows unwritten
    const bf16* asrc = A + (size_t)am * K + skc;
    const bf16* bsrc = W + (size_t)sr * K + skc;

    bf16x8_t apre = {};
    if (tid < 256) apre = *(const bf16x8_t*)(asrc);
    bf16x8_t bpre[4];
    #pragma unroll
    for (int p = 0; p < 4; ++p)
        bpre[p] = *(const bf16x8_t*)(bsrc + (size_t)(p * 64) * K);

    for (int k0 = 0; k0 < K; k0 += 64) {
        if (tid < 256) *(bf16x8_t*)(&As[sr * 72 + skc]) = apre;
        #pragma unroll
        for (int p = 0; p < 4; ++p)
            *(bf16x8_t*)(&Bs[(p * 64 + sr) * 72 + skc]) = bpre[p];
        __syncthreads();
        if (k0 + 64 < K) {
            if (tid < 256) apre = *(const bf16x8_t*)(asrc + k0 + 64);
            #pragma unroll
            for (int p = 0; p < 4; ++p)
                bpre[p] = *(const bf16x8_t*)(bsrc + (size_t)(p * 64) * K + k0 + 64);
        }
        #pragma unroll
        for (int ks = 0; ks < 2; ++ks) {
            bf16x8_t a[2], b[2];
            #pragma unroll
            for (int mi = 0; mi < 2; ++mi)
                a[mi] = *(bf16x8_t*)(&As[(mi * 16 + l16) * 72 + ks * 32 + quad * 8]);
            #pragma unroll
            for (int ni = 0; ni < 2; ++ni)
                b[ni] = *(bf16x8_t*)(&Bs[(wave * 32 + ni * 16 + l16) * 72 + ks * 32 + quad * 8]);
            #pragma unroll
            for (int mi = 0; mi < 2; ++mi)
                #pragma unroll
                for (int ni = 0; ni < 2; ++ni)
                    acc[mi][ni] = __builtin_amdgcn_mfma_f32_16x16x32_bf16(a[mi], b[ni], acc[mi][ni], 0, 0, 0);
        }
        __syncthreads();
    }
    // epilogue: bias (+residual), per-row mean/var across 8 waves, normalize, write
    float v[2][2][4];
    float bcol[2];
    #pragma unroll
    for (int ni = 0; ni < 2; ++ni) bcol[ni] = bias[wave * 32 + ni * 16 + l16];
    #pragma unroll
    for (int mi = 0; mi < 2; ++mi) {
        #pragma unroll
        for (int r = 0; r < 4; ++r) {
            int row = mi * 16 + quad * 4 + r;
            int mrow = m0 + row;
            float s = 0.f, s2 = 0.f;
            #pragma unroll
            for (int ni = 0; ni < 2; ++ni) {
                float x = acc[mi][ni][r] + bcol[ni];
                if (RES && mrow < M)
                    x += bf(R[(size_t)mrow * N + wave * 32 + ni * 16 + l16]);
                v[mi][ni][r] = x;
                s += x; s2 += x * x;
            }
            #pragma unroll
            for (int off = 1; off < 16; off <<= 1) {
                s  += __shfl_xor(s, off);
                s2 += __shfl_xor(s2, off);
            }
            if (l16 == 0) { red[0][row][wave] = s; red[1][row][wave] = s2; }
        }
    }
    __syncthreads();
    #pragma unroll
    for (int mi = 0; mi < 2; ++mi) {
        #pragma unroll
        for (int r = 0; r < 4; ++r) {
            int row = mi * 16 + quad * 4 + r;
            int mrow = m0 + row;
            if (mrow >= M) continue;
            float sum = 0.f, sq = 0.f;
            #pragma unroll
            for (int w8 = 0; w8 < 8; ++w8) { sum += red[0][row][w8]; sq += red[1][row][w8]; }
            float mean = sum * (1.f / 256.f);
            float var  = sq * (1.f / 256.f) - mean * mean;
            float rstd = rsqrtf(var + EPS_LN);
            #pragma unroll
            for (int ni = 0; ni < 2; ++ni) {
                int col = wave * 32 + ni * 16 + l16;
                out[(size_t)mrow * N + col] =
                    tobf((v[mi][ni][r] - mean) * rstd * g[col] + bb[col]);
            }
        }
    }
}

// ---------------- fused QKV GEMM v3: gload_lds(16)+swizzle staging + bias/RoPE --------
// Same staging transformation as gemm_bf128 v3. V (part==2) -> V^T flat-m [h][d][M_PAD]
// via LDS-transpose epilogue (T overlaid on the linear As+Bs region). K (part==1) ->
// KHD [b*8+h][t][d]. Q scaled by 1/sqrt(32).
__global__ __launch_bounds__(256) void gemm_qkv128(const bf16* __restrict__ A,
    const bf16* __restrict__ Wqkv, const float* __restrict__ bq,
    const float* __restrict__ bk, const float* __restrict__ bv,
    bf16* __restrict__ qo, bf16* __restrict__ ko, bf16* __restrict__ vo, int M)
{
    const int K = 256, N = 256;
    __shared__ short sh[128 * 64 + 64 * 64];   // As | Bs (24KB); T overlays sh (8704 shorts)
    short* Asl = sh;
    short* Bsl = sh + 128 * 64;
    int part = blockIdx.y >> 2;
    int n0 = (blockIdx.y & 3) * 64;
    const bf16* W     = Wqkv + (size_t)part * 65536;
    const float* bias = (part == 0) ? bq : (part == 1) ? bk : bv;
    float oscale = (part == 0) ? ATTN_SCALE : 1.0f;

    int tid = threadIdx.x;
    int wave = tid >> 6, lane = tid & 63, quad = lane >> 4, l16 = lane & 15;
    int wm = wave & 1, wn = wave >> 1;
    int m0 = blockIdx.x * 128;

    f32x4_t zero4 = {0.f, 0.f, 0.f, 0.f};
    f32x4_t acc[4][2];
    #pragma unroll
    for (int i = 0; i < 4; ++i) { acc[i][0] = zero4; acc[i][1] = zero4; }

    int lr8 = lane >> 3, lcb = lane & 7;

    for (int k0 = 0; k0 < K; k0 += 64) {
        #pragma unroll
        for (int i = 0; i < 4; ++i) {
            int row = (wave * 4 + i) * 8 + lr8;
            int m = m0 + row; if (m >= M) m = M - 1;
            int cb = lcb ^ (row & 7);
            gl_lds16(A + (size_t)m * K + k0 + cb * 8, &Asl[(wave * 4 + i) * 512]);
        }
        #pragma unroll
        for (int i = 0; i < 2; ++i) {
            int row = (wave * 2 + i) * 8 + lr8;
            int cb = lcb ^ (row & 7);
            gl_lds16(W + (size_t)(n0 + row) * K + k0 + cb * 8, &Bsl[(wave * 2 + i) * 512]);
        }
        __syncthreads();
        #pragma unroll
        for (int ks = 0; ks < 2; ++ks) {
            bf16x8_t a[4], b[2];
            #pragma unroll
            for (int mi = 0; mi < 4; ++mi) {
                int row = wm * 64 + mi * 16 + l16;
                a[mi] = *(bf16x8_t*)(&Asl[row * 64 + ((ks * 4 + quad) ^ (row & 7)) * 8]);
            }
            #pragma unroll
            for (int ni = 0; ni < 2; ++ni) {
                int row = wn * 32 + ni * 16 + l16;
                b[ni] = *(bf16x8_t*)(&Bsl[row * 64 + ((ks * 4 + quad) ^ (row & 7)) * 8]);
            }
            #pragma unroll
            for (int mi = 0; mi < 4; ++mi)
                #pragma unroll
                for (int ni = 0; ni < 2; ++ni)
                    acc[mi][ni] = __builtin_amdgcn_mfma_f32_16x16x32_bf16(a[mi], b[ni], acc[mi][ni], 0, 0, 0);
        }
        __syncthreads();
    }
    int col0 = n0 + wn * 32 + l16;          // d = l16 within this head
    float b1v = bias[col0], b2v = bias[col0 + 16];
    if (part == 2) {
        // Transpose through LDS: T [64 col][128 m + 8 pad], stride 136 (8704 <= 12288).
        short* T = sh;
        int colA = wn * 32 + l16;
        #pragma unroll
        for (int mi = 0; mi < 4; ++mi) {
            #pragma unroll
            for (int r = 0; r < 4; ++r) {
                int mrow = wm * 64 + mi * 16 + quad * 4 + r;
                T[colA * 136 + mrow]        = bfbits(acc[mi][0][r] + b1v);
                T[(colA + 16) * 136 + mrow] = bfbits(acc[mi][1][r] + b2v);
            }
        }
        __syncthreads();
        // Coalesced V^T stores: 8 lanes per col cover 128B contiguous in m.
        int c8 = tid >> 3, mo = (tid & 7) * 8;
        #pragma unroll
        for (int cc = 0; cc < 2; ++cc) {
            int col = c8 + cc * 32;
            int rowidx = ((n0 >> 5) + (col >> 5)) * HDIM + (col & 31);  // h*32 + d
            #pragma unroll
            for (int mm = 0; mm < 2; ++mm) {
                int m = mo + mm * 64;
                *(bf16x8_t*)(vo + (size_t)rowidx * M_PAD + m0 + m) =
                    *(bf16x8_t*)(&T[col * 136 + m]);
            }
        }
    } else {
        int hA = (n0 >> 5) + wn;            // head index of this wave's column group
        float invf = powf(10000.f, -(float)l16 * (1.f / 16.f));
        #pragma unroll
        for (int mi = 0; mi < 4; ++mi) {
            #pragma unroll
            for (int r = 0; r < 4; ++r) {
                int row = m0 + wm * 64 + mi * 16 + quad * 4 + r;
                if (row >= M) continue;
                int bb = row / S_LEN, t = row - bb * S_LEN;
                float x1 = acc[mi][0][r] + b1v;
                float x2 = acc[mi][1][r] + b2v;
                float ang = (float)t * invf;
                float sn, cs;
                __sincosf(ang, &sn, &cs);
                float y1 = (x1 * cs - x2 * sn) * oscale;
                float y2 = (x1 * sn + x2 * cs) * oscale;
                if (part == 0) {
                    size_t obase = ((size_t)bb * S_PAD + t) * N;
                    qo[obase + col0]      = tobf(y1);
                    qo[obase + col0 + 16] = tobf(y2);
                } else {
                    // KHD: [(b*8+h)][t][d], d contiguous (32B segment per quad)
                    size_t kbase = ((size_t)(bb * NHEAD + hA) * S_PAD + t) * HDIM;
                    ko[kbase + l16]      = tobf(y1);
                    ko[kbase + l16 + 16] = tobf(y2);
                }
            }
        }
    }
}

// ---------------- assemble h ----------------
__global__ __launch_bounds__(256) void assemble_h(const bf16* __restrict__ tmp,
    const float* __restrict__ cls, bf16* __restrict__ h)
{
    int row = blockIdx.x;
    int tid = threadIdx.x;
    int b = row / S_LEN, t = row % S_LEN;
    bf16 v = (t == 0) ? tobf(cls[tid]) : tmp[((size_t)(b * 1024 + t - 1)) * E_DIM + tid];
    h[(size_t)row * E_DIM + tid] = v;
}

// ---------------- MFMA flash attention v7 (R12): KHD K, swapped QK, b64 P-writes ------
__global__ __launch_bounds__(256) void attn_mfma(const bf16* __restrict__ Q,
    const bf16* __restrict__ KT, const bf16* __restrict__ VT, bf16* __restrict__ O)
{
    __shared__ short Ks[2][64 * 40];      // [buf][s][d], stride 40 shorts
    __shared__ short Vs[2][32 * 72];      // [buf][d][s], stride 72 shorts
    __shared__ short Ps[4][16 * 72];      // [wave][q][s], per-wave
    int blk = blockIdx.x;
    int bh = blk & 63;                    // XCD-locality swizzle
    int qt = blk >> 6;
    int hh = bh & 7, b = bh >> 3;
    int tid = threadIdx.x;
    int wave = tid >> 6, lane = tid & 63, quad = lane >> 4, l16 = lane & 15;
    int q0 = qt * 64 + wave * 16;
    const size_t bSp = (size_t)b * S_PAD;
    const size_t bS  = (size_t)b * S_LEN;
    const size_t hoff = (size_t)hh * HDIM;
    const bf16* Qb = Q + bSp * E_DIM + hoff;
    const bf16* KTb = KT + (size_t)(b * NHEAD + hh) * S_PAD * HDIM;   // [t][d]

    f32x4_t zero4 = {0.f, 0.f, 0.f, 0.f};
    bf16x8_t qfrag = *(const bf16x8_t*)(Qb + (size_t)(q0 + l16) * E_DIM + quad * 8);
    f32x4_t o0 = zero4, o1 = zero4;
    float lsum = 0.f;
    short* myP = Ps[wave];

    int ksr = tid >> 2, kdc = (tid & 3) * 8;
    int vd  = tid >> 3, vsc = (tid & 7) * 8;
    const bf16* ksrc = KTb + tid * 8;     // contiguous chunk: elem (s*32+d) = tid*8
    const bf16* vsrc = VT + ((size_t)(hh * HDIM + vd)) * M_PAD + bS + vsc;
    bf16x8_t kpre = *(const bf16x8_t*)(ksrc);
    bf16x8_t vpre = *(const bf16x8_t*)(vsrc);

    for (int c = 0; c < 17; ++c) {
        int s0 = c * 64;
        short* Kl = Ks[c & 1];
        short* Vl = Vs[c & 1];
        *(bf16x8_t*)(&Kl[ksr * 40 + kdc]) = kpre;
        *(bf16x8_t*)(&Vl[vd * 72 + vsc]) = vpre;
        __syncthreads();
        if (c < 16) {
            kpre = *(const bf16x8_t*)(ksrc + (size_t)(c + 1) * 64 * HDIM);
            vpre = *(const bf16x8_t*)(vsrc + s0 + 64);
        }
        f32x4_t sc[4];
        #pragma unroll
        for (int kk = 0; kk < 4; ++kk) {
            bf16x8_t kf = *(bf16x8_t*)(&Kl[(kk * 16 + l16) * 40 + quad * 8]);
            // swapped operands: A=K, B=Q -> C = S^T: sc[kk][r] = S[q=l16][s0+16kk+4quad+r]
            sc[kk] = __builtin_amdgcn_mfma_f32_16x16x32_bf16(kf, qfrag, zero4, 0, 0, 0);
        }
        #pragma unroll
        for (int kk = 0; kk < 4; ++kk) {
            bf16x4_t pk;
            #pragma unroll
            for (int r = 0; r < 4; ++r) {
                int s = s0 + kk * 16 + quad * 4 + r;
                float raw = (s < S_LEN) ? sc[kk][r] : -1e30f;
                float p = __expf(raw);
                lsum += p;
                pk[r] = bfbits(p);
            }
            *(bf16x4_t*)(&myP[l16 * 72 + kk * 16 + quad * 4]) = pk;
        }
        asm volatile("s_waitcnt lgkmcnt(0)" ::: "memory");
        __builtin_amdgcn_sched_barrier(0);
        #pragma unroll
        for (int half = 0; half < 2; ++half) {
            int off = half * 32 + quad * 8;
            bf16x8_t pf  = *(bf16x8_t*)(&myP[l16 * 72 + off]);
            bf16x8_t vf0 = *(bf16x8_t*)(&Vl[l16 * 72 + off]);
            bf16x8_t vf1 = *(bf16x8_t*)(&Vl[(16 + l16) * 72 + off]);
            o0 = __builtin_amdgcn_mfma_f32_16x16x32_bf16(pf, vf0, o0, 0, 0, 0);
            o1 = __builtin_amdgcn_mfma_f32_16x16x32_bf16(pf, vf1, o1, 0, 0, 0);
        }
    }
    // row-sum: lane holds partial for q-row l16; reduce across the 4 quads (lanes ^16,^32)
    float tot = lsum;
    tot += __shfl_xor(tot, 16);
    tot += __shfl_xor(tot, 32);
    #pragma unroll
    for (int r = 0; r < 4; ++r) {
        int qrow = q0 + quad * 4 + r;
        float rsum = __shfl(tot, quad * 4 + r);   // row-sum for q = quad*4+r (lane l16=q)
        if (qrow < S_LEN) {
            float rs = 1.f / rsum;
            O[(bS + qrow) * E_DIM + hoff + l16]      = tobf(o0[r] * rs);
            O[(bS + qrow) * E_DIM + hoff + 16 + l16] = tobf(o1[r] * rs);
        }
    }
}

// ---------------- final head ----------------
__global__ __launch_bounds__(256) void ts_kernel(const bf16* __restrict__ H,
    const float* __restrict__ w, const float* __restrict__ tb,
    float* __restrict__ out)
{
    int wid = (blockIdx.x << 2) + (threadIdx.x >> 6);
    int lane = threadIdx.x & 63;
    int b = wid >> 10, t = wid & 1023;
    const bf16* row = H + ((size_t)(b * S_LEN + t + 1)) * E_DIM;
    float acc = 0.f;
    for (int e = lane; e < E_DIM; e += 64) acc += bf(row[e]) * w[e];
    #pragma unroll
    for (int off = 32; off; off >>= 1) acc += __shfl_down(acc, off, 64);
    if (lane == 0) out[wid] = acc + tb[0];
}

// ---------------- host launch ----------------
extern "C" void kernel_launch(void* const* d_in, const int* in_sizes, int n_in,
                              void* d_out, int out_size, void* d_ws, size_t ws_size,
                              hipStream_t stream)
{
    (void)in_sizes; (void)n_in; (void)out_size; (void)ws_size;
    const float* X        = (const float*)d_in[0];
    const float* CONV1_DW = (const float*)d_in[1];
    const float* CONV1_PW = (const float*)d_in[2];
    const float* BN1_G    = (const float*)d_in[3];
    const float* BN1_B    = (const float*)d_in[4];
    const float* CONV2_DW = (const float*)d_in[5];
    const float* CONV2_PW = (const float*)d_in[6];
    const float* BN2_G    = (const float*)d_in[7];
    const float* BN2_B    = (const float*)d_in[8];
    const float* PROJ_W   = (const float*)d_in[9];
    const float* PROJ_B   = (const float*)d_in[10];
    const float* CLS      = (const float*)d_in[11];
    const float* WQ       = (const float*)d_in[12];
    const float* BQ       = (const float*)d_in[13];
    const float* WK       = (const float*)d_in[14];
    const float* BK       = (const float*)d_in[15];
    const float* WV       = (const float*)d_in[16];
    const float* BV       = (const float*)d_in[17];
    const float* WO       = (const float*)d_in[18];
    const float* BO       = (const float*)d_in[19];
    const float* LN1G     = (const float*)d_in[20];
    const float* LN1B     = (const float*)d_in[21];
    const float* W1       = (const float*)d_in[22];
    const float* B1       = (const float*)d_in[23];
    const float* W2       = (const float*)d_in[24];
    const float* B2       = (const float*)d_in[25];
    const float* LN2G     = (const float*)d_in[26];
    const float* LN2B     = (const float*)d_in[27];
    const float* LATW     = (const float*)d_in[28];
    const float* LATB     = (const float*)d_in[29];
    const float* LATNG    = (const float*)d_in[30];
    const float* LATNB    = (const float*)d_in[31];
    const float* TSW      = (const float*)d_in[32];
    const float* TSB      = (const float*)d_in[33];

    const size_t SROW  = (size_t)MROWS * E_DIM;       // 2,099,200
    const size_t SPROW = (size_t)8 * S_PAD * E_DIM;   // 2,228,224 (q padded; KHD/V^T = exactly this)
    bf16* h    = (bf16*)d_ws;
    bf16* bufB = h + SROW;
    bf16* r0   = bufB + SROW;
    bf16* q  = r0;                     // padded stride S_PAD per batch
    bf16* k  = r0 + SPROW;             // KHD layout: [b*8+h][S_PAD][32]
    bf16* v  = r0 + 2 * SPROW;         // V^T layout: [h][d][M_PAD] flat-m
    bf16* cx = r0 + 3 * SPROW;         // compact (SROW)
    bf16* wall = cx + SROW;            // 6 layer slots, 6*WSLOT elems
    bf16* pslot = wall + 6 * WSLOT;    // proj/lat slot (65536 elems)
    bf16* y1 = r0;
    bf16* y2 = r0 + SROW;
    bf16* mid = r0;                    // MLP hidden 4*SROW <= r0 region size

    conv_sep1<<<dim3(512), dim3(256), 0, stream>>>(X, CONV1_DW, CONV1_PW, BN1_G, BN1_B, y1);
    conv_sep2<<<dim3(256), dim3(256), 0, stream>>>(y1, CONV2_DW, CONV2_PW, BN2_G, BN2_B, y2);
    cvt_w<<<dim3(32), dim3(256), 0, stream>>>(PROJ_W, pslot, 32768);
    gemm_bf<0><<<dim3(128, 4), dim3(256), 0, stream>>>(y2, pslot, PROJ_B, bufB, 8192, 256, 128);
    assemble_h<<<dim3(MROWS), dim3(256), 0, stream>>>(bufB, CLS, h);
    // convert all six layers' weights in ONE dispatch
    cvt_layer6<<<dim3(768, 6), dim3(256), 0, stream>>>(WQ, WK, WV, WO, W1, W2, wall);

    for (int l = 0; l < 6; ++l) {
        bf16* wslot = wall + (size_t)l * WSLOT;
        gemm_qkv128<<<dim3(65, 12), dim3(256), 0, stream>>>(h, wslot,
            BQ + l * 256, BK + l * 256, BV + l * 256, q, k, v, MROWS);
        attn_mfma<<<dim3(64 * 17), dim3(256), 0, stream>>>(q, k, v, cx);
        gemm_resln<1><<<dim3(257), dim3(512), 0, stream>>>(cx, wslot + 196608,
            BO + l * 256, h, LN1G + l * 256, LN1B + l * 256, h, MROWS, 256);
        gemm_bf128<1><<<dim3(65, 16), dim3(256), 0, stream>>>(h, wslot + 262144, B1 + l * 1024, mid, MROWS, 1024, 256);
        gemm_resln<1><<<dim3(257), dim3(512), 0, stream>>>(mid, wslot + 524288,
            B2 + l * 256, h, LN2G + l * 256, LN2B + l * 256, h, MROWS, 1024);
    }

    cvt_w<<<dim3(64), dim3(256), 0, stream>>>(LATW, pslot, 65536);
    gemm_resln<0><<<dim3(257), dim3(512), 0, stream>>>(h, pslot, LATB, nullptr,
        LATNG, LATNB, r0, MROWS, 256);
    ts_kernel<<<dim3(2048), dim3(256), 0, stream>>>(r0, TSW, TSB, (float*)d_out);
}

// Round 14
// 743.827 us; speedup vs baseline: 1.0325x; 1.0325x over previous
//
#include <hip/hip_runtime.h>
#include <hip/hip_bf16.h>
#include <math.h>

typedef __hip_bfloat16 bf16;
typedef __attribute__((ext_vector_type(8))) short bf16x8_t;   // MFMA A/B frag (4 VGPRs)
typedef __attribute__((ext_vector_type(4))) short bf16x4_t;
typedef __attribute__((ext_vector_type(4))) float f32x4_t;    // MFMA C/D frag

// ---------------- constants ----------------
#define BN_RDENOM 0.9999950000374997f   // 1/sqrt(1+1e-5)
#define EPS_LN 1e-5f
#define ATTN_SCALE 0.17677669529663687f // 1/sqrt(32)
#define S_LEN 1025
#define S_PAD 1088                      // 17*64, for unconditional chunked loads
#define E_DIM 256
#define NHEAD 8
#define HDIM 32
#define MROWS (8 * S_LEN)               // 8200
#define M_PAD 8320                      // 65*128: flat-m V^T row length (>= 7*1025+1088)
#define WSLOT 786432                    // bf16 elems per layer weight slot

__device__ __forceinline__ float bf(const bf16 v) { return __bfloat162float(v); }
__device__ __forceinline__ bf16 tobf(float v) { return __float2bfloat16(v); }
__device__ __forceinline__ short bfbits(float v) {
    bf16 t = __float2bfloat16(v); short s; __builtin_memcpy(&s, &t, 2); return s;
}
__device__ __forceinline__ float gelu_exact(float x) {
    return 0.5f * x * (1.0f + erff(x * 0.70710678118654752f));
}

// ---------------- weight conversion fp32 -> bf16 ----------------
__global__ __launch_bounds__(256) void cvt_w(const float* __restrict__ src,
    bf16* __restrict__ dst, int n)
{
    int i = (blockIdx.x * 256 + threadIdx.x) * 4;
    if (i >= n) return;
    f32x4_t v = *(const f32x4_t*)(src + i);
    bf16x4_t o;
    #pragma unroll
    for (int j = 0; j < 4; ++j) o[j] = bfbits(v[j]);
    *(bf16x4_t*)((short*)dst + i) = o;
}

// all six weight tensors of one layer into one slot, ALL LAYERS in one dispatch:
// grid (768, 6); blockIdx.y = layer. [Wq 64K][Wk 64K][Wv 64K][Wo 64K][W1 256K][W2 256K].
__global__ __launch_bounds__(256) void cvt_layer6(const float* __restrict__ wq,
    const float* __restrict__ wk, const float* __restrict__ wv, const float* __restrict__ wo,
    const float* __restrict__ w1, const float* __restrict__ w2, bf16* __restrict__ dst)
{
    int l = blockIdx.y;
    int i = (blockIdx.x * 256 + threadIdx.x) * 4;
    const float* s; int off;
    if (i < 262144) {
        s = (i < 65536) ? wq : (i < 131072) ? wk : (i < 196608) ? wv : wo;
        s += (size_t)l * 65536;
        off = i & 65535;
    } else if (i < 524288) { s = w1 + (size_t)l * 262144; off = i - 262144; }
    else                   { s = w2 + (size_t)l * 262144; off = i - 524288; }
    f32x4_t v = *(const f32x4_t*)(s + off);
    bf16x4_t o;
    #pragma unroll
    for (int j = 0; j < 4; ++j) o[j] = bfbits(v[j]);
    *(bf16x4_t*)((short*)dst + (size_t)l * WSLOT + i) = o;
}

// ---------------- conv block 1 ----------------
__global__ __launch_bounds__(256) void conv_sep1(const float* __restrict__ x,
    const float* __restrict__ dw, const float* __restrict__ pw,
    const float* __restrict__ g, const float* __restrict__ bb,
    bf16* __restrict__ out)
{
    __shared__ float xs[70][64];
    __shared__ float dy[32][64];
    __shared__ float pws[64][65];
    __shared__ float dws[64][7];
    int blk = blockIdx.x;
    int tile = blk & 63, b = blk >> 6;
    int t0 = tile * 32;
    int tid = threadIdx.x;
    int tbase = t0 * 2 - 3;
    for (int i = tid; i < 70 * 64; i += 256) {
        int r = i >> 6, c = i & 63;
        int t = tbase + r;
        xs[r][c] = (t >= 0 && t < 4096) ? x[((size_t)b * 4096 + t) * 64 + c] : 0.f;
    }
    for (int i = tid; i < 64 * 7; i += 256) dws[i / 7][i % 7] = dw[i];
    for (int i = tid; i < 64 * 64; i += 256) pws[i >> 6][i & 63] = pw[i];
    __syncthreads();
    for (int i = tid; i < 32 * 64; i += 256) {
        int tl = i >> 6, c = i & 63;
        float s = 0.f;
        #pragma unroll
        for (int j = 0; j < 7; ++j) s += xs[2 * tl + j][c] * dws[c][j];
        dy[tl][c] = s;
    }
    __syncthreads();
    for (int i = tid; i < 32 * 64; i += 256) {
        int tl = i >> 6, o = i & 63;
        float s = 0.f;
        #pragma unroll 8
        for (int c = 0; c < 64; ++c) s += dy[tl][c] * pws[o][c];
        s = s * BN_RDENOM * g[o] + bb[o];
        out[((size_t)(b * 2048 + t0 + tl)) * 64 + o] = tobf(gelu_exact(s));
    }
}

// ---------------- conv block 2 ----------------
__global__ __launch_bounds__(256) void conv_sep2(const bf16* __restrict__ x,
    const float* __restrict__ dw, const float* __restrict__ pw,
    const float* __restrict__ g, const float* __restrict__ bb,
    bf16* __restrict__ out)
{
    __shared__ float xs[70][64];
    __shared__ float dy[32][64];
    __shared__ float pws[128][65];
    __shared__ float dws[64][7];
    int blk = blockIdx.x;
    int tile = blk & 31, b = blk >> 5;
    int t0 = tile * 32;
    int tid = threadIdx.x;
    int tbase = t0 * 2 - 3;
    for (int i = tid; i < 70 * 64; i += 256) {
        int r = i >> 6, c = i & 63;
        int t = tbase + r;
        xs[r][c] = (t >= 0 && t < 2048) ? bf(x[((size_t)b * 2048 + t) * 64 + c]) : 0.f;
    }
    for (int i = tid; i < 64 * 7; i += 256) dws[i / 7][i % 7] = dw[i];
    for (int i = tid; i < 128 * 64; i += 256) pws[i >> 6][i & 63] = pw[i];
    __syncthreads();
    for (int i = tid; i < 32 * 64; i += 256) {
        int tl = i >> 6, c = i & 63;
        float s = 0.f;
        #pragma unroll
        for (int j = 0; j < 7; ++j) s += xs[2 * tl + j][c] * dws[c][j];
        dy[tl][c] = s;
    }
    __syncthreads();
    for (int i = tid; i < 32 * 128; i += 256) {
        int tl = i >> 7, o = i & 127;
        float s = 0.f;
        #pragma unroll 8
        for (int c = 0; c < 64; ++c) s += dy[tl][c] * pws[o][c];
        s = s * BN_RDENOM * g[o] + bb[o];
        out[((size_t)(b * 1024 + t0 + tl)) * 128 + o] = tobf(gelu_exact(s));
    }
}

// ---------------- MFMA GEMM (R12-measured): all-bf16, BK=64, 64x64 tile ----------------
template <int ACT>
__global__ __launch_bounds__(256) void gemm_bf(const bf16* __restrict__ A,
    const bf16* __restrict__ W, const float* __restrict__ bias,
    bf16* __restrict__ C, int M, int N, int K)
{
    __shared__ short As[64 * 72];
    __shared__ short Bs[64 * 72];
    int tid = threadIdx.x;
    int wave = tid >> 6, lane = tid & 63, quad = lane >> 4, l16 = lane & 15;
    int wm = wave & 1, wn = wave >> 1;
    int m0 = blockIdx.x * 64, n0 = blockIdx.y * 64;

    f32x4_t zero4 = {0.f, 0.f, 0.f, 0.f};
    f32x4_t acc[2][2];
    acc[0][0] = zero4; acc[0][1] = zero4; acc[1][0] = zero4; acc[1][1] = zero4;

    int srow = tid >> 2, skc = (tid & 3) * 16;
    for (int k0 = 0; k0 < K; k0 += 64) {
        {
            int m = m0 + srow;
            bf16x8_t a0 = {}, a1 = {};
            if (m < M) {
                a0 = *(const bf16x8_t*)(A + (size_t)m * K + k0 + skc);
                a1 = *(const bf16x8_t*)(A + (size_t)m * K + k0 + skc + 8);
            }
            *(bf16x8_t*)(&As[srow * 72 + skc])     = a0;
            *(bf16x8_t*)(&As[srow * 72 + skc + 8]) = a1;
        }
        {
            const bf16* wp = W + (size_t)(n0 + srow) * K + k0 + skc;
            *(bf16x8_t*)(&Bs[srow * 72 + skc])     = *(const bf16x8_t*)(wp);
            *(bf16x8_t*)(&Bs[srow * 72 + skc + 8]) = *(const bf16x8_t*)(wp + 8);
        }
        __syncthreads();
        #pragma unroll
        for (int ks = 0; ks < 2; ++ks) {
            bf16x8_t a[2], b[2];
            #pragma unroll
            for (int mi = 0; mi < 2; ++mi)
                a[mi] = *(bf16x8_t*)(&As[(wm * 32 + mi * 16 + l16) * 72 + ks * 32 + quad * 8]);
            #pragma unroll
            for (int ni = 0; ni < 2; ++ni)
                b[ni] = *(bf16x8_t*)(&Bs[(wn * 32 + ni * 16 + l16) * 72 + ks * 32 + quad * 8]);
            #pragma unroll
            for (int mi = 0; mi < 2; ++mi)
                #pragma unroll
                for (int ni = 0; ni < 2; ++ni)
                    acc[mi][ni] = __builtin_amdgcn_mfma_f32_16x16x32_bf16(a[mi], b[ni], acc[mi][ni], 0, 0, 0);
        }
        __syncthreads();
    }
    #pragma unroll
    for (int mi = 0; mi < 2; ++mi) {
        #pragma unroll
        for (int ni = 0; ni < 2; ++ni) {
            int col = n0 + wn * 32 + ni * 16 + l16;
            float bv = bias[col];
            #pragma unroll
            for (int r = 0; r < 4; ++r) {
                int row = m0 + wm * 32 + mi * 16 + quad * 4 + r;
                if (row < M) {
                    float v = acc[mi][ni][r] + bv;
                    if (ACT == 1) v = gelu_exact(v);
                    C[(size_t)row * N + col] = tobf(v);
                }
            }
        }
    }
}

// ---------------- MFMA GEMM 128x64 (R10-measured, MLP-up): 4 waves of 64x32, BK=64 ----
// No register prefetch (R11: regresses at multi-block/CU occupancy); no gload_lds
// (R13: regresses at small K — drain at barrier + permuted-source coalescing loss).
template <int ACT>
__global__ __launch_bounds__(256) void gemm_bf128(const bf16* __restrict__ A,
    const bf16* __restrict__ W, const float* __restrict__ bias,
    bf16* __restrict__ C, int M, int N, int K)
{
    __shared__ short As[128 * 72];
    __shared__ short Bs[64 * 72];
    int tid = threadIdx.x;
    int wave = tid >> 6, lane = tid & 63, quad = lane >> 4, l16 = lane & 15;
    int wm = wave & 1, wn = wave >> 1;
    int m0 = blockIdx.x * 128, n0 = blockIdx.y * 64;

    f32x4_t zero4 = {0.f, 0.f, 0.f, 0.f};
    f32x4_t acc[4][2];
    #pragma unroll
    for (int i = 0; i < 4; ++i) { acc[i][0] = zero4; acc[i][1] = zero4; }

    int srow = tid >> 2, skc = (tid & 3) * 16;
    for (int k0 = 0; k0 < K; k0 += 64) {
        #pragma unroll
        for (int p = 0; p < 2; ++p) {
            int row = srow + p * 64;
            int m = m0 + row;
            bf16x8_t a0 = {}, a1 = {};
            if (m < M) {
                a0 = *(const bf16x8_t*)(A + (size_t)m * K + k0 + skc);
                a1 = *(const bf16x8_t*)(A + (size_t)m * K + k0 + skc + 8);
            }
            *(bf16x8_t*)(&As[row * 72 + skc])     = a0;
            *(bf16x8_t*)(&As[row * 72 + skc + 8]) = a1;
        }
        {
            const bf16* wp = W + (size_t)(n0 + srow) * K + k0 + skc;
            *(bf16x8_t*)(&Bs[srow * 72 + skc])     = *(const bf16x8_t*)(wp);
            *(bf16x8_t*)(&Bs[srow * 72 + skc + 8]) = *(const bf16x8_t*)(wp + 8);
        }
        __syncthreads();
        #pragma unroll
        for (int ks = 0; ks < 2; ++ks) {
            bf16x8_t a[4], b[2];
            #pragma unroll
            for (int mi = 0; mi < 4; ++mi)
                a[mi] = *(bf16x8_t*)(&As[(wm * 64 + mi * 16 + l16) * 72 + ks * 32 + quad * 8]);
            #pragma unroll
            for (int ni = 0; ni < 2; ++ni)
                b[ni] = *(bf16x8_t*)(&Bs[(wn * 32 + ni * 16 + l16) * 72 + ks * 32 + quad * 8]);
            #pragma unroll
            for (int mi = 0; mi < 4; ++mi)
                #pragma unroll
                for (int ni = 0; ni < 2; ++ni)
                    acc[mi][ni] = __builtin_amdgcn_mfma_f32_16x16x32_bf16(a[mi], b[ni], acc[mi][ni], 0, 0, 0);
        }
        __syncthreads();
    }
    #pragma unroll
    for (int mi = 0; mi < 4; ++mi) {
        #pragma unroll
        for (int ni = 0; ni < 2; ++ni) {
            int col = n0 + wn * 32 + ni * 16 + l16;
            float bv = bias[col];
            #pragma unroll
            for (int r = 0; r < 4; ++r) {
                int row = m0 + wm * 64 + mi * 16 + quad * 4 + r;
                if (row < M) {
                    float v = acc[mi][ni][r] + bv;
                    if (ACT == 1) v = gelu_exact(v);
                    C[(size_t)row * N + col] = tobf(v);
                }
            }
        }
    }
}

// ---------------- fused GEMM (N=256) + bias + residual + LayerNorm (512 thr) -----------
// 32 rows x 256 cols per block, 8 waves each 32x32 -> 2 waves/SIMD at 1 block/CU.
// Register prefetch kept HERE (1 block/CU: no TLP to hide staging latency).
template <int RES>
__global__ __launch_bounds__(512) void gemm_resln(const bf16* __restrict__ A,
    const bf16* __restrict__ W, const float* __restrict__ bias,
    const bf16* __restrict__ R, const float* __restrict__ g,
    const float* __restrict__ bb, bf16* __restrict__ out, int M, int K)
{
    const int N = 256;
    __shared__ short As[32 * 72];
    __shared__ short Bs[256 * 72];
    __shared__ float red[2][32][8];
    int tid = threadIdx.x;
    int wave = tid >> 6, lane = tid & 63, quad = lane >> 4, l16 = lane & 15;
    int m0 = blockIdx.x * 32;

    f32x4_t zero4 = {0.f, 0.f, 0.f, 0.f};
    f32x4_t acc[2][2];
    acc[0][0] = zero4; acc[0][1] = zero4; acc[1][0] = zero4; acc[1][1] = zero4;

    int sr = tid >> 3, skc = (tid & 7) * 8;
    int am = m0 + sr; if (am >= M) am = M - 1;   // clamp: finite, rows unwritten
    const bf16* asrc = A + (size_t)am * K + skc;
    const bf16* bsrc = W + (size_t)sr * K + skc;

    bf16x8_t apre = {};
    if (tid < 256) apre = *(const bf16x8_t*)(asrc);
    bf16x8_t bpre[4];
    #pragma unroll
    for (int p = 0; p < 4; ++p)
        bpre[p] = *(const bf16x8_t*)(bsrc + (size_t)(p * 64) * K);

    for (int k0 = 0; k0 < K; k0 += 64) {
        if (tid < 256) *(bf16x8_t*)(&As[sr * 72 + skc]) = apre;
        #pragma unroll
        for (int p = 0; p < 4; ++p)
            *(bf16x8_t*)(&Bs[(p * 64 + sr) * 72 + skc]) = bpre[p];
        __syncthreads();
        if (k0 + 64 < K) {
            if (tid < 256) apre = *(const bf16x8_t*)(asrc + k0 + 64);
            #pragma unroll
            for (int p = 0; p < 4; ++p)
                bpre[p] = *(const bf16x8_t*)(bsrc + (size_t)(p * 64) * K + k0 + 64);
        }
        #pragma unroll
        for (int ks = 0; ks < 2; ++ks) {
            bf16x8_t a[2], b[2];
            #pragma unroll
            for (int mi = 0; mi < 2; ++mi)
                a[mi] = *(bf16x8_t*)(&As[(mi * 16 + l16) * 72 + ks * 32 + quad * 8]);
            #pragma unroll
            for (int ni = 0; ni < 2; ++ni)
                b[ni] = *(bf16x8_t*)(&Bs[(wave * 32 + ni * 16 + l16) * 72 + ks * 32 + quad * 8]);
            #pragma unroll
            for (int mi = 0; mi < 2; ++mi)
                #pragma unroll
                for (int ni = 0; ni < 2; ++ni)
                    acc[mi][ni] = __builtin_amdgcn_mfma_f32_16x16x32_bf16(a[mi], b[ni], acc[mi][ni], 0, 0, 0);
        }
        __syncthreads();
    }
    // epilogue: bias (+residual), per-row mean/var across 8 waves, normalize, write
    float v[2][2][4];
    float bcol[2];
    #pragma unroll
    for (int ni = 0; ni < 2; ++ni) bcol[ni] = bias[wave * 32 + ni * 16 + l16];
    #pragma unroll
    for (int mi = 0; mi < 2; ++mi) {
        #pragma unroll
        for (int r = 0; r < 4; ++r) {
            int row = mi * 16 + quad * 4 + r;
            int mrow = m0 + row;
            float s = 0.f, s2 = 0.f;
            #pragma unroll
            for (int ni = 0; ni < 2; ++ni) {
                float x = acc[mi][ni][r] + bcol[ni];
                if (RES && mrow < M)
                    x += bf(R[(size_t)mrow * N + wave * 32 + ni * 16 + l16]);
                v[mi][ni][r] = x;
                s += x; s2 += x * x;
            }
            #pragma unroll
            for (int off = 1; off < 16; off <<= 1) {
                s  += __shfl_xor(s, off);
                s2 += __shfl_xor(s2, off);
            }
            if (l16 == 0) { red[0][row][wave] = s; red[1][row][wave] = s2; }
        }
    }
    __syncthreads();
    #pragma unroll
    for (int mi = 0; mi < 2; ++mi) {
        #pragma unroll
        for (int r = 0; r < 4; ++r) {
            int row = mi * 16 + quad * 4 + r;
            int mrow = m0 + row;
            if (mrow >= M) continue;
            float sum = 0.f, sq = 0.f;
            #pragma unroll
            for (int w8 = 0; w8 < 8; ++w8) { sum += red[0][row][w8]; sq += red[1][row][w8]; }
            float mean = sum * (1.f / 256.f);
            float var  = sq * (1.f / 256.f) - mean * mean;
            float rstd = rsqrtf(var + EPS_LN);
            #pragma unroll
            for (int ni = 0; ni < 2; ++ni) {
                int col = wave * 32 + ni * 16 + l16;
                out[(size_t)mrow * N + col] =
                    tobf((v[mi][ni][r] - mean) * rstd * g[col] + bb[col]);
            }
        }
    }
}

// ---------------- fused QKV GEMM + bias + RoPE + Q-scale ----------------
// V (part==2) -> V^T flat-m [h][d][M_PAD] (LDS-transpose epilogue, coalesced 16B).
// K (part==1) -> KHD layout [b*8+h][t][d] (d contiguous). Q scaled by 1/sqrt(32).
__global__ __launch_bounds__(256) void gemm_qkv128(const bf16* __restrict__ A,
    const bf16* __restrict__ Wqkv, const float* __restrict__ bq,
    const float* __restrict__ bk, const float* __restrict__ bv,
    bf16* __restrict__ qo, bf16* __restrict__ ko, bf16* __restrict__ vo, int M)
{
    const int K = 256, N = 256;
    __shared__ short As[128 * 72];
    __shared__ short Bs[64 * 72];
    int part = blockIdx.y >> 2;
    int n0 = (blockIdx.y & 3) * 64;
    const bf16* W     = Wqkv + (size_t)part * 65536;
    const float* bias = (part == 0) ? bq : (part == 1) ? bk : bv;
    float oscale = (part == 0) ? ATTN_SCALE : 1.0f;

    int tid = threadIdx.x;
    int wave = tid >> 6, lane = tid & 63, quad = lane >> 4, l16 = lane & 15;
    int wm = wave & 1, wn = wave >> 1;
    int m0 = blockIdx.x * 128;

    f32x4_t zero4 = {0.f, 0.f, 0.f, 0.f};
    f32x4_t acc[4][2];
    #pragma unroll
    for (int i = 0; i < 4; ++i) { acc[i][0] = zero4; acc[i][1] = zero4; }

    int srow = tid >> 2, skc = (tid & 3) * 16;
    for (int k0 = 0; k0 < K; k0 += 64) {
        #pragma unroll
        for (int p = 0; p < 2; ++p) {
            int row = srow + p * 64;
            int m = m0 + row;
            bf16x8_t a0 = {}, a1 = {};
            if (m < M) {
                a0 = *(const bf16x8_t*)(A + (size_t)m * K + k0 + skc);
                a1 = *(const bf16x8_t*)(A + (size_t)m * K + k0 + skc + 8);
            }
            *(bf16x8_t*)(&As[row * 72 + skc])     = a0;
            *(bf16x8_t*)(&As[row * 72 + skc + 8]) = a1;
        }
        {
            const bf16* wp = W + (size_t)(n0 + srow) * K + k0 + skc;
            *(bf16x8_t*)(&Bs[srow * 72 + skc])     = *(const bf16x8_t*)(wp);
            *(bf16x8_t*)(&Bs[srow * 72 + skc + 8]) = *(const bf16x8_t*)(wp + 8);
        }
        __syncthreads();
        #pragma unroll
        for (int ks = 0; ks < 2; ++ks) {
            bf16x8_t a[4], b[2];
            #pragma unroll
            for (int mi = 0; mi < 4; ++mi)
                a[mi] = *(bf16x8_t*)(&As[(wm * 64 + mi * 16 + l16) * 72 + ks * 32 + quad * 8]);
            #pragma unroll
            for (int ni = 0; ni < 2; ++ni)
                b[ni] = *(bf16x8_t*)(&Bs[(wn * 32 + ni * 16 + l16) * 72 + ks * 32 + quad * 8]);
            #pragma unroll
            for (int mi = 0; mi < 4; ++mi)
                #pragma unroll
                for (int ni = 0; ni < 2; ++ni)
                    acc[mi][ni] = __builtin_amdgcn_mfma_f32_16x16x32_bf16(a[mi], b[ni], acc[mi][ni], 0, 0, 0);
        }
        __syncthreads();
    }
    int col0 = n0 + wn * 32 + l16;          // d = l16 within this head
    float b1v = bias[col0], b2v = bias[col0 + 16];
    if (part == 2) {
        // Transpose through LDS (reuse As): T [64 col][128 m + 8 pad], stride 136.
        short* T = As;
        int colA = wn * 32 + l16;
        #pragma unroll
        for (int mi = 0; mi < 4; ++mi) {
            #pragma unroll
            for (int r = 0; r < 4; ++r) {
                int mrow = wm * 64 + mi * 16 + quad * 4 + r;
                T[colA * 136 + mrow]        = bfbits(acc[mi][0][r] + b1v);
                T[(colA + 16) * 136 + mrow] = bfbits(acc[mi][1][r] + b2v);
            }
        }
        __syncthreads();
        // Coalesced V^T stores: 8 lanes per col cover 128B contiguous in m.
        int c8 = tid >> 3, mo = (tid & 7) * 8;
        #pragma unroll
        for (int cc = 0; cc < 2; ++cc) {
            int col = c8 + cc * 32;
            int rowidx = ((n0 >> 5) + (col >> 5)) * HDIM + (col & 31);  // h*32 + d
            #pragma unroll
            for (int mm = 0; mm < 2; ++mm) {
                int m = mo + mm * 64;
                *(bf16x8_t*)(vo + (size_t)rowidx * M_PAD + m0 + m) =
                    *(bf16x8_t*)(&T[col * 136 + m]);
            }
        }
    } else {
        int hA = (n0 >> 5) + wn;            // head index of this wave's column group
        float invf = powf(10000.f, -(float)l16 * (1.f / 16.f));
        #pragma unroll
        for (int mi = 0; mi < 4; ++mi) {
            #pragma unroll
            for (int r = 0; r < 4; ++r) {
                int row = m0 + wm * 64 + mi * 16 + quad * 4 + r;
                if (row >= M) continue;
                int bb = row / S_LEN, t = row - bb * S_LEN;
                float x1 = acc[mi][0][r] + b1v;
                float x2 = acc[mi][1][r] + b2v;
                float ang = (float)t * invf;
                float sn, cs;
                __sincosf(ang, &sn, &cs);
                float y1 = (x1 * cs - x2 * sn) * oscale;
                float y2 = (x1 * sn + x2 * cs) * oscale;
                if (part == 0) {
                    size_t obase = ((size_t)bb * S_PAD + t) * N;
                    qo[obase + col0]      = tobf(y1);
                    qo[obase + col0 + 16] = tobf(y2);
                } else {
                    // KHD: [(b*8+h)][t][d], d contiguous (32B segment per quad)
                    size_t kbase = ((size_t)(bb * NHEAD + hA) * S_PAD + t) * HDIM;
                    ko[kbase + l16]      = tobf(y1);
                    ko[kbase + l16 + 16] = tobf(y2);
                }
            }
        }
    }
}

// ---------------- assemble h ----------------
__global__ __launch_bounds__(256) void assemble_h(const bf16* __restrict__ tmp,
    const float* __restrict__ cls, bf16* __restrict__ h)
{
    int row = blockIdx.x;
    int tid = threadIdx.x;
    int b = row / S_LEN, t = row % S_LEN;
    bf16 v = (t == 0) ? tobf(cls[tid]) : tmp[((size_t)(b * 1024 + t - 1)) * E_DIM + tid];
    h[(size_t)row * E_DIM + tid] = v;
}

// ---------------- MFMA flash attention v7 (R12-verified): KHD K, swapped QK ----------
__global__ __launch_bounds__(256) void attn_mfma(const bf16* __restrict__ Q,
    const bf16* __restrict__ KT, const bf16* __restrict__ VT, bf16* __restrict__ O)
{
    __shared__ short Ks[2][64 * 40];      // [buf][s][d], stride 40 shorts
    __shared__ short Vs[2][32 * 72];      // [buf][d][s], stride 72 shorts
    __shared__ short Ps[4][16 * 72];      // [wave][q][s], per-wave
    int blk = blockIdx.x;
    int bh = blk & 63;                    // XCD-locality swizzle
    int qt = blk >> 6;
    int hh = bh & 7, b = bh >> 3;
    int tid = threadIdx.x;
    int wave = tid >> 6, lane = tid & 63, quad = lane >> 4, l16 = lane & 15;
    int q0 = qt * 64 + wave * 16;
    const size_t bSp = (size_t)b * S_PAD;
    const size_t bS  = (size_t)b * S_LEN;
    const size_t hoff = (size_t)hh * HDIM;
    const bf16* Qb = Q + bSp * E_DIM + hoff;
    const bf16* KTb = KT + (size_t)(b * NHEAD + hh) * S_PAD * HDIM;   // [t][d]

    f32x4_t zero4 = {0.f, 0.f, 0.f, 0.f};
    bf16x8_t qfrag = *(const bf16x8_t*)(Qb + (size_t)(q0 + l16) * E_DIM + quad * 8);
    f32x4_t o0 = zero4, o1 = zero4;
    float lsum = 0.f;
    short* myP = Ps[wave];

    int ksr = tid >> 2, kdc = (tid & 3) * 8;
    int vd  = tid >> 3, vsc = (tid & 7) * 8;
    const bf16* ksrc = KTb + tid * 8;     // contiguous chunk: elem (s*32+d) = tid*8
    const bf16* vsrc = VT + ((size_t)(hh * HDIM + vd)) * M_PAD + bS + vsc;
    bf16x8_t kpre = *(const bf16x8_t*)(ksrc);
    bf16x8_t vpre = *(const bf16x8_t*)(vsrc);

    for (int c = 0; c < 17; ++c) {
        int s0 = c * 64;
        short* Kl = Ks[c & 1];
        short* Vl = Vs[c & 1];
        *(bf16x8_t*)(&Kl[ksr * 40 + kdc]) = kpre;
        *(bf16x8_t*)(&Vl[vd * 72 + vsc]) = vpre;
        __syncthreads();
        if (c < 16) {
            kpre = *(const bf16x8_t*)(ksrc + (size_t)(c + 1) * 64 * HDIM);
            vpre = *(const bf16x8_t*)(vsrc + s0 + 64);
        }
        f32x4_t sc[4];
        #pragma unroll
        for (int kk = 0; kk < 4; ++kk) {
            bf16x8_t kf = *(bf16x8_t*)(&Kl[(kk * 16 + l16) * 40 + quad * 8]);
            // swapped operands: A=K, B=Q -> C = S^T: sc[kk][r] = S[q=l16][s0+16kk+4quad+r]
            sc[kk] = __builtin_amdgcn_mfma_f32_16x16x32_bf16(kf, qfrag, zero4, 0, 0, 0);
        }
        #pragma unroll
        for (int kk = 0; kk < 4; ++kk) {
            bf16x4_t pk;
            #pragma unroll
            for (int r = 0; r < 4; ++r) {
                int s = s0 + kk * 16 + quad * 4 + r;
                float raw = (s < S_LEN) ? sc[kk][r] : -1e30f;
                float p = __expf(raw);
                lsum += p;
                pk[r] = bfbits(p);
            }
            *(bf16x4_t*)(&myP[l16 * 72 + kk * 16 + quad * 4]) = pk;
        }
        asm volatile("s_waitcnt lgkmcnt(0)" ::: "memory");
        __builtin_amdgcn_sched_barrier(0);
        #pragma unroll
        for (int half = 0; half < 2; ++half) {
            int off = half * 32 + quad * 8;
            bf16x8_t pf  = *(bf16x8_t*)(&myP[l16 * 72 + off]);
            bf16x8_t vf0 = *(bf16x8_t*)(&Vl[l16 * 72 + off]);
            bf16x8_t vf1 = *(bf16x8_t*)(&Vl[(16 + l16) * 72 + off]);
            o0 = __builtin_amdgcn_mfma_f32_16x16x32_bf16(pf, vf0, o0, 0, 0, 0);
            o1 = __builtin_amdgcn_mfma_f32_16x16x32_bf16(pf, vf1, o1, 0, 0, 0);
        }
    }
    // row-sum: lane holds partial for q-row l16; reduce across the 4 quads (lanes ^16,^32)
    float tot = lsum;
    tot += __shfl_xor(tot, 16);
    tot += __shfl_xor(tot, 32);
    #pragma unroll
    for (int r = 0; r < 4; ++r) {
        int qrow = q0 + quad * 4 + r;
        float rsum = __shfl(tot, quad * 4 + r);   // row-sum for q = quad*4+r (lane l16=q)
        if (qrow < S_LEN) {
            float rs = 1.f / rsum;
            O[(bS + qrow) * E_DIM + hoff + l16]      = tobf(o0[r] * rs);
            O[(bS + qrow) * E_DIM + hoff + 16 + l16] = tobf(o1[r] * rs);
        }
    }
}

// ---------------- final head ----------------
__global__ __launch_bounds__(256) void ts_kernel(const bf16* __restrict__ H,
    const float* __restrict__ w, const float* __restrict__ tb,
    float* __restrict__ out)
{
    int wid = (blockIdx.x << 2) + (threadIdx.x >> 6);
    int lane = threadIdx.x & 63;
    int b = wid >> 10, t = wid & 1023;
    const bf16* row = H + ((size_t)(b * S_LEN + t + 1)) * E_DIM;
    float acc = 0.f;
    for (int e = lane; e < E_DIM; e += 64) acc += bf(row[e]) * w[e];
    #pragma unroll
    for (int off = 32; off; off >>= 1) acc += __shfl_down(acc, off, 64);
    if (lane == 0) out[wid] = acc + tb[0];
}

// ---------------- host launch ----------------
extern "C" void kernel_launch(void* const* d_in, const int* in_sizes, int n_in,
                              void* d_out, int out_size, void* d_ws, size_t ws_size,
                              hipStream_t stream)
{
    (void)in_sizes; (void)n_in; (void)out_size; (void)ws_size;
    const float* X        = (const float*)d_in[0];
    const float* CONV1_DW = (const float*)d_in[1];
    const float* CONV1_PW = (const float*)d_in[2];
    const float* BN1_G    = (const float*)d_in[3];
    const float* BN1_B    = (const float*)d_in[4];
    const float* CONV2_DW = (const float*)d_in[5];
    const float* CONV2_PW = (const float*)d_in[6];
    const float* BN2_G    = (const float*)d_in[7];
    const float* BN2_B    = (const float*)d_in[8];
    const float* PROJ_W   = (const float*)d_in[9];
    const float* PROJ_B   = (const float*)d_in[10];
    const float* CLS      = (const float*)d_in[11];
    const float* WQ       = (const float*)d_in[12];
    const float* BQ       = (const float*)d_in[13];
    const float* WK       = (const float*)d_in[14];
    const float* BK       = (const float*)d_in[15];
    const float* WV       = (const float*)d_in[16];
    const float* BV       = (const float*)d_in[17];
    const float* WO       = (const float*)d_in[18];
    const float* BO       = (const float*)d_in[19];
    const float* LN1G     = (const float*)d_in[20];
    const float* LN1B     = (const float*)d_in[21];
    const float* W1       = (const float*)d_in[22];
    const float* B1       = (const float*)d_in[23];
    const float* W2       = (const float*)d_in[24];
    const float* B2       = (const float*)d_in[25];
    const float* LN2G     = (const float*)d_in[26];
    const float* LN2B     = (const float*)d_in[27];
    const float* LATW     = (const float*)d_in[28];
    const float* LATB     = (const float*)d_in[29];
    const float* LATNG    = (const float*)d_in[30];
    const float* LATNB    = (const float*)d_in[31];
    const float* TSW      = (const float*)d_in[32];
    const float* TSB      = (const float*)d_in[33];

    const size_t SROW  = (size_t)MROWS * E_DIM;       // 2,099,200
    const size_t SPROW = (size_t)8 * S_PAD * E_DIM;   // 2,228,224 (q padded; KHD/V^T = exactly this)
    bf16* h    = (bf16*)d_ws;
    bf16* bufB = h + SROW;
    bf16* r0   = bufB + SROW;
    bf16* q  = r0;                     // padded stride S_PAD per batch
    bf16* k  = r0 + SPROW;             // KHD layout: [b*8+h][S_PAD][32]
    bf16* v  = r0 + 2 * SPROW;         // V^T layout: [h][d][M_PAD] flat-m
    bf16* cx = r0 + 3 * SPROW;         // compact (SROW)
    bf16* wall = cx + SROW;            // 6 layer slots, 6*WSLOT elems
    bf16* pslot = wall + 6 * WSLOT;    // proj/lat slot (65536 elems)
    bf16* y1 = r0;
    bf16* y2 = r0 + SROW;
    bf16* mid = r0;                    // MLP hidden 4*SROW <= r0 region size

    conv_sep1<<<dim3(512), dim3(256), 0, stream>>>(X, CONV1_DW, CONV1_PW, BN1_G, BN1_B, y1);
    conv_sep2<<<dim3(256), dim3(256), 0, stream>>>(y1, CONV2_DW, CONV2_PW, BN2_G, BN2_B, y2);
    cvt_w<<<dim3(32), dim3(256), 0, stream>>>(PROJ_W, pslot, 32768);
    gemm_bf<0><<<dim3(128, 4), dim3(256), 0, stream>>>(y2, pslot, PROJ_B, bufB, 8192, 256, 128);
    assemble_h<<<dim3(MROWS), dim3(256), 0, stream>>>(bufB, CLS, h);
    // convert all six layers' weights in ONE dispatch
    cvt_layer6<<<dim3(768, 6), dim3(256), 0, stream>>>(WQ, WK, WV, WO, W1, W2, wall);

    for (int l = 0; l < 6; ++l) {
        bf16* wslot = wall + (size_t)l * WSLOT;
        gemm_qkv128<<<dim3(65, 12), dim3(256), 0, stream>>>(h, wslot,
            BQ + l * 256, BK + l * 256, BV + l * 256, q, k, v, MROWS);
        attn_mfma<<<dim3(64 * 17), dim3(256), 0, stream>>>(q, k, v, cx);
        gemm_resln<1><<<dim3(257), dim3(512), 0, stream>>>(cx, wslot + 196608,
            BO + l * 256, h, LN1G + l * 256, LN1B + l * 256, h, MROWS, 256);
        gemm_bf128<1><<<dim3(65, 16), dim3(256), 0, stream>>>(h, wslot + 262144, B1 + l * 1024, mid, MROWS, 1024, 256);
        gemm_resln<1><<<dim3(257), dim3(512), 0, stream>>>(mid, wslot + 524288,
            B2 + l * 256, h, LN2G + l * 256, LN2B + l * 256, h, MROWS, 1024);
    }

    cvt_w<<<dim3(64), dim3(256), 0, stream>>>(LATW, pslot, 65536);
    gemm_resln<0><<<dim3(257), dim3(512), 0, stream>>>(h, pslot, LATB, nullptr,
        LATNG, LATNB, r0, MROWS, 256);
    ts_kernel<<<dim3(2048), dim3(256), 0, stream>>>(r0, TSW, TSB, (float*)d_out);
}